// Round 1
// baseline (228.378 us; speedup 1.0000x reference)
//
#include <hip/hip_runtime.h>
#include <math.h>

#define BB 2
#define CC 256
#define LL 512   // H == W == L

__device__ __forceinline__ float gelu_exact(float x) {
    return 0.5f * x * (1.0f + erff(x * 0.70710678118654752f));
}

// 1) gather diagonal: diag[bc*L + l] = feat[(bc*L + l)*L + l]
__global__ void k_gather(const float* __restrict__ feat, float* __restrict__ diag) {
    int idx = blockIdx.x * blockDim.x + threadIdx.x;  // B*C*L
    if (idx >= BB * CC * LL) return;
    int l = idx & (LL - 1);
    long long bc = idx >> 9;
    diag[idx] = feat[(bc * LL + l) * LL + l];
}

// 2) grouped conv1d (groups=8) + bias + exact GELU
__global__ void k_conv1(const float* __restrict__ diag, const float* __restrict__ w1,
                        const float* __restrict__ b1, float* __restrict__ x1) {
    int idx = blockIdx.x * blockDim.x + threadIdx.x;  // (b*C + o)*L + l, l fastest
    if (idx >= BB * CC * LL) return;
    int l = idx & (LL - 1);
    int o = (idx >> 9) & (CC - 1);
    int b = idx >> 17;
    int g = o >> 5;  // group, 32 out-ch per group
    const float* dg = diag + ((b * CC + (g << 5)) << 9);  // base of 32 input channels
    const float* wp = w1 + o * 96;                        // w1[o, i, k], 32*3
    float acc = b1[o];
    #pragma unroll
    for (int k = 0; k < 3; ++k) {
        int p = l + k - 1;
        if (p < 0 || p >= LL) continue;
        #pragma unroll 8
        for (int i = 0; i < 32; ++i)
            acc += dg[(i << 9) + p] * wp[i * 3 + k];
    }
    x1[idx] = gelu_exact(acc);
}

// 3) transpose w2 [o][c][k] -> w2t [(c*3+k)*C + o] for coalesced loads in conv2
__global__ void k_transpose_w2(const float* __restrict__ w2, float* __restrict__ w2t) {
    int idx = blockIdx.x * blockDim.x + threadIdx.x;  // o*768 + c*3 + k
    if (idx >= CC * CC * 3) return;
    int o = idx / 768;
    int ck = idx - o * 768;
    w2t[ck * CC + o] = w2[idx];
}

// 4) dense conv1d + bias + exact GELU, LDS-staged input tile
#define TL 4
__global__ __launch_bounds__(256) void k_conv2(const float* __restrict__ x1,
                                               const float* __restrict__ w2t,
                                               const float* __restrict__ b2,
                                               float* __restrict__ x2) {
    __shared__ float s[CC * (TL + 2)];
    int blk = blockIdx.x;               // b * (L/TL) + lt
    int b = blk / (LL / TL);
    int l0 = (blk - b * (LL / TL)) * TL;
    int o = threadIdx.x;
    for (int t = threadIdx.x; t < CC * (TL + 2); t += 256) {
        int c = t / (TL + 2);
        int j = t - c * (TL + 2);
        int p = l0 + j - 1;
        s[t] = (p >= 0 && p < LL) ? x1[((b * CC + c) << 9) + p] : 0.0f;
    }
    __syncthreads();
    float acc[TL];
    #pragma unroll
    for (int j = 0; j < TL; ++j) acc[j] = b2[o];
    for (int c = 0; c < CC; ++c) {
        float w0 = w2t[(c * 3 + 0) * CC + o];
        float w1v = w2t[(c * 3 + 1) * CC + o];
        float w2v = w2t[(c * 3 + 2) * CC + o];
        const float* sc = s + c * (TL + 2);   // broadcast reads: conflict-free
        #pragma unroll
        for (int j = 0; j < TL; ++j)
            acc[j] += sc[j] * w0 + sc[j + 1] * w1v + sc[j + 2] * w2v;
    }
    #pragma unroll
    for (int j = 0; j < TL; ++j)
        x2[((b * CC + o) << 9) + l0 + j] = gelu_exact(acc[j]);
}

// 5) fused writer: zeros everywhere + band |j-i|<=2, float4 stores
__global__ void k_write(const float* __restrict__ x2, const float* __restrict__ wb,
                        float4* __restrict__ out) {
    const long long N4 = (long long)BB * CC * LL * LL / 4;  // 33,554,432
    long long stride = (long long)gridDim.x * blockDim.x;
    for (long long idx4 = (long long)blockIdx.x * blockDim.x + threadIdx.x; idx4 < N4;
         idx4 += stride) {
        long long flat = idx4 << 2;
        int j0 = (int)(flat & (LL - 1));
        int i  = (int)((flat >> 9) & (LL - 1));
        int bc = (int)(flat >> 18);
        float4 v = make_float4(0.f, 0.f, 0.f, 0.f);
        if (j0 >= i - 5 && j0 <= i + 2) {
            const float* xr = x2 + ((long long)bc << 9);
            float xm = (i > 0)       ? xr[i - 1] : 0.0f;
            float x0 = xr[i];
            float xp = (i < LL - 1)  ? xr[i + 1] : 0.0f;
            const float* w = wb + (bc & (CC - 1)) * 9;  // w_blur[c,0,ki,kj]
            float vals[4];
            #pragma unroll
            for (int t = 0; t < 4; ++t) {
                int d = (j0 + t) - i;
                float r = 0.f;
                if (d == -2)      r = w[2] * xm;
                else if (d == -1) r = w[1] * xm + w[5] * x0;
                else if (d == 0)  r = w[0] * xm + w[4] * x0 + w[8] * xp;
                else if (d == 1)  r = w[3] * x0 + w[7] * xp;
                else if (d == 2)  r = w[6] * xp;
                vals[t] = r;
            }
            v = make_float4(vals[0], vals[1], vals[2], vals[3]);
        }
        out[idx4] = v;
    }
}

extern "C" void kernel_launch(void* const* d_in, const int* in_sizes, int n_in,
                              void* d_out, int out_size, void* d_ws, size_t ws_size,
                              hipStream_t stream) {
    const float* feat   = (const float*)d_in[0];
    const float* w1     = (const float*)d_in[1];
    const float* b1     = (const float*)d_in[2];
    const float* w2     = (const float*)d_in[3];
    const float* b2     = (const float*)d_in[4];
    const float* w_blur = (const float*)d_in[5];
    float* out = (float*)d_out;
    float* ws  = (float*)d_ws;

    const int N = BB * CC * LL;      // 262144
    float* diag = ws;                // [N]
    float* x1   = ws + N;            // [N]
    float* x2   = ws + 2 * N;        // [N]
    float* w2t  = ws + 3 * N;        // [C*C*3] = 196608

    k_gather<<<N / 256, 256, 0, stream>>>(feat, diag);
    k_transpose_w2<<<(CC * CC * 3 + 255) / 256, 256, 0, stream>>>(w2, w2t);
    k_conv1<<<N / 256, 256, 0, stream>>>(diag, w1, b1, x1);
    k_conv2<<<BB * (LL / TL), 256, 0, stream>>>(x1, w2t, b2, x2);
    k_write<<<2048, 256, 0, stream>>>(x2, w_blur, (float4*)out);
}

// Round 2
// 217.220 us; speedup vs baseline: 1.0514x; 1.0514x over previous
//
#include <hip/hip_runtime.h>
#include <math.h>

#define BB 2
#define CC 256
#define LL 512   // H == W == L

__device__ __forceinline__ float gelu_exact(float x) {
    return 0.5f * x * (1.0f + erff(x * 0.70710678118654752f));
}

// 1) gather diagonal: diag[bc*L + l] = feat[(bc*L + l)*L + l]
__global__ void k_gather(const float* __restrict__ feat, float* __restrict__ diag) {
    int idx = blockIdx.x * blockDim.x + threadIdx.x;  // B*C*L
    if (idx >= BB * CC * LL) return;
    int l = idx & (LL - 1);
    long long bc = idx >> 9;
    diag[idx] = feat[(bc * LL + l) * LL + l];
}

// 2) grouped conv1d (groups=8) + bias + exact GELU; 3 acc chains
__global__ void k_conv1(const float* __restrict__ diag, const float* __restrict__ w1,
                        const float* __restrict__ b1, float* __restrict__ x1) {
    int idx = blockIdx.x * blockDim.x + threadIdx.x;  // (b*C + o)*L + l, l fastest
    if (idx >= BB * CC * LL) return;
    int l = idx & (LL - 1);
    int o = (idx >> 9) & (CC - 1);
    int b = idx >> 17;
    const float* dg = diag + ((b * CC + ((o >> 5) << 5)) << 9);  // 32-ch group base
    const float* wp = w1 + o * 96;                               // wave-uniform
    float a0 = 0.f, a1 = 0.f, a2 = 0.f;
    bool hm = (l > 0), hp = (l < LL - 1);
    #pragma unroll
    for (int i = 0; i < 32; ++i) {
        const float* dc = dg + (i << 9);
        float dm = hm ? dc[l - 1] : 0.f;
        float d0 = dc[l];
        float dp = hp ? dc[l + 1] : 0.f;
        a0 += dm * wp[i * 3 + 0];
        a1 += d0 * wp[i * 3 + 1];
        a2 += dp * wp[i * 3 + 2];
    }
    x1[idx] = gelu_exact(a0 + a1 + a2 + b1[o]);
}

// 3) transpose w2 [o][c][k] -> w2t [(c*3+k)*C + o]
__global__ void k_transpose_w2(const float* __restrict__ w2, float* __restrict__ w2t) {
    int idx = blockIdx.x * blockDim.x + threadIdx.x;
    if (idx >= CC * CC * 3) return;
    int o = idx / 768;
    int ck = idx - o * 768;
    w2t[ck * CC + o] = w2[idx];
}

// 4) dense conv1d + bias + exact GELU
//    block = (b, l-tile of 8, o-chunk of 64); 512 blocks, 256 threads
#define TL2 8
__global__ __launch_bounds__(256) void k_conv2(const float* __restrict__ x1,
                                               const float* __restrict__ w2t,
                                               const float* __restrict__ b2,
                                               float* __restrict__ x2) {
    __shared__ float s[CC][TL2 + 2];
    int blk = blockIdx.x;
    int oc = blk & 3;
    int lt = (blk >> 2) & 63;
    int b  = blk >> 8;
    int l0 = lt * TL2;
    for (int t = threadIdx.x; t < CC * (TL2 + 2); t += 256) {
        int c = t / (TL2 + 2);
        int j = t - c * (TL2 + 2);
        int p = l0 + j - 1;
        s[c][j] = (p >= 0 && p < LL) ? x1[((b * CC + c) << 9) + p] : 0.0f;
    }
    __syncthreads();
    int o  = (oc << 6) + (threadIdx.x & 63);   // lanes: consecutive o -> coalesced w loads
    int jg = threadIdx.x >> 6;                 // wave-uniform -> LDS broadcasts
    float bias = b2[o];
    float acc0 = bias, acc1 = bias;
    const float* wp = w2t + o;
    #pragma unroll 4
    for (int c = 0; c < CC; ++c) {
        float w0  = wp[c * 768];
        float w1v = wp[c * 768 + 256];
        float w2v = wp[c * 768 + 512];
        float s0 = s[c][jg * 2 + 0];
        float s1 = s[c][jg * 2 + 1];
        float s2 = s[c][jg * 2 + 2];
        float s3 = s[c][jg * 2 + 3];
        acc0 += s0 * w0 + s1 * w1v + s2 * w2v;
        acc1 += s1 * w0 + s2 * w1v + s3 * w2v;
    }
    int l = l0 + jg * 2;
    float* xo = x2 + ((b * CC + o) << 9) + l;
    xo[0] = gelu_exact(acc0);
    xo[1] = gelu_exact(acc1);
}

// 5) band writer: only the 5 floats per output row that are nonzero
//    (the rest of d_out was zeroed by hipMemsetAsync)
__global__ void k_band(const float* __restrict__ x2, const float* __restrict__ wb,
                       float* __restrict__ out) {
    int idx = blockIdx.x * blockDim.x + threadIdx.x;  // bc*L + i
    if (idx >= BB * CC * LL) return;
    int i = idx & (LL - 1);
    int bc = idx >> 9;
    const float* xr = x2 + (bc << 9);
    float xm = (i > 0)      ? xr[i - 1] : 0.f;
    float x0 = xr[i];
    float xp = (i < LL - 1) ? xr[i + 1] : 0.f;
    const float* w = wb + (bc & (CC - 1)) * 9;  // w_blur[c,0,ki,kj]
    float v0 = w[2] * xm;                       // j = i-2  (ki,kj)=(0,2)
    float v1 = w[1] * xm + w[5] * x0;           // j = i-1
    float v2 = w[0] * xm + w[4] * x0 + w[8] * xp; // j = i
    float v3 = w[3] * x0 + w[7] * xp;           // j = i+1
    float v4 = w[6] * xp;                       // j = i+2
    float* row = out + ((long long)bc << 18) + ((long long)i << 9);
    if (i >= 2)      row[i - 2] = v0;
    if (i >= 1)      row[i - 1] = v1;
    row[i] = v2;
    if (i <= LL - 2) row[i + 1] = v3;
    if (i <= LL - 3) row[i + 2] = v4;
}

extern "C" void kernel_launch(void* const* d_in, const int* in_sizes, int n_in,
                              void* d_out, int out_size, void* d_ws, size_t ws_size,
                              hipStream_t stream) {
    const float* feat   = (const float*)d_in[0];
    const float* w1     = (const float*)d_in[1];
    const float* b1     = (const float*)d_in[2];
    const float* w2     = (const float*)d_in[3];
    const float* b2     = (const float*)d_in[4];
    const float* w_blur = (const float*)d_in[5];
    float* out = (float*)d_out;
    float* ws  = (float*)d_ws;

    const int N = BB * CC * LL;      // 262144
    float* diag = ws;                // [N]
    float* x1   = ws + N;            // [N]
    float* x2   = ws + 2 * N;        // [N]
    float* w2t  = ws + 3 * N;        // [C*C*3]

    // zero the full output at vendor-fill speed (graph-capturable)
    hipMemsetAsync(out, 0, (size_t)out_size * sizeof(float), stream);

    k_gather<<<N / 256, 256, 0, stream>>>(feat, diag);
    k_transpose_w2<<<(CC * CC * 3 + 255) / 256, 256, 0, stream>>>(w2, w2t);
    k_conv1<<<N / 256, 256, 0, stream>>>(diag, w1, b1, x1);
    k_conv2<<<BB * (LL / TL2) * 4, 256, 0, stream>>>(x1, w2t, b2, x2);
    k_band<<<N / 256, 256, 0, stream>>>(x2, w_blur, out);
}